// Round 7
// baseline (1618.802 us; speedup 1.0000x reference)
//
#include <hip/hip_runtime.h>

#define HD 64
#define KP 16            // timesteps per phase (one workgroup barrier per phase)
#define NS 32            // ring slots = 2 phases (double buffer)
#define L2E 1.4426950408889634f

typedef _Float16 v2h __attribute__((ext_vector_type(2)));
typedef _Float16 v4h __attribute__((ext_vector_type(4)));
typedef _Float16 h8  __attribute__((ext_vector_type(8)));

__device__ __forceinline__ float fexp2(float x) { return __builtin_amdgcn_exp2f(x); }
__device__ __forceinline__ float frcp(float x)  { return __builtin_amdgcn_rcpf(x); }
__device__ __forceinline__ float ftanh_fast(float x) {
    return 1.f - 2.f * frcp(fexp2(2.f * L2E * x) + 1.f);
}
__device__ __forceinline__ float fsig(float x) {
    return frcp(fexp2(-L2E * x) + 1.f);
}

#if __has_builtin(__builtin_amdgcn_fdot2)
__device__ __forceinline__ float FDOT2(v2h a, v2h b, float c) {
    return __builtin_amdgcn_fdot2(a, b, c, false);
}
#else
__device__ __forceinline__ float FDOT2(v2h a, v2h b, float c) {
    return fmaf((float)a.x, (float)b.x, fmaf((float)a.y, (float)b.y, c));
}
#endif

// R6 post-mortem: 3 rounds of forcing register-resident weights (launch
// bounds, LDS pad, num_vgpr, readfirstlane-uniform branches, asm pins) all
// ended at VGPR_Count=140 + scratch spill (50MB cold-touch FETCH, 21-41ms
// first dispatch). The RA's own cost model chooses scratch for the 128-VGPR
// weight set; not controllable from HIP source. Pivot: weights become
// LDS-RESIDENT in a TRANSPOSED conflict-free layout.
//   wlds[m][gate][qq][row] : v4h (8B) = k-elems 4qq..4qq+3 of `row`.
//   Lane j reads [..][j] -> 64 lanes x 8B stride = 2 lanes/bank = FREE
//   (m136: 2-way is 1.02x). Row-major would be a 32-way conflict (G4).
// Per step the 3 matvec waves read 96KB of weights; LDS array at 256B/cy
// -> ~384 cy/step, vs ~1100 cy/step on the scratch/L1 path.
// Dot pairing (even k-pairs -> acc0, odd -> acc1) matches the validated
// kernel exactly -> bit-identical sums, absmax unchanged.

// 4-gate 64-dot from LDS weights: 8 x (1 ds_read_b128 h + 8 ds_read_b64 w
// + 16 v_dot2_f32_f16).
#define DOTLDS4(M, HP) do { \
    _Pragma("unroll") \
    for (int q = 0; q < 8; ++q) { \
        h8 hv_ = (HP)[q]; \
        v2h p0_={hv_[0],hv_[1]}, p1_={hv_[2],hv_[3]}; \
        v2h p2_={hv_[4],hv_[5]}, p3_={hv_[6],hv_[7]}; \
        v4h wA0 = wlds[M][0][2*q][lane], wA1 = wlds[M][0][2*q+1][lane]; \
        v4h wB0 = wlds[M][1][2*q][lane], wB1 = wlds[M][1][2*q+1][lane]; \
        v4h wC0 = wlds[M][2][2*q][lane], wC1 = wlds[M][2][2*q+1][lane]; \
        v4h wD0 = wlds[M][3][2*q][lane], wD1 = wlds[M][3][2*q+1][lane]; \
        a00 = FDOT2(v2h{wA0[0],wA0[1]}, p0_, a00); \
        a01 = FDOT2(v2h{wA0[2],wA0[3]}, p1_, a01); \
        a00 = FDOT2(v2h{wA1[0],wA1[1]}, p2_, a00); \
        a01 = FDOT2(v2h{wA1[2],wA1[3]}, p3_, a01); \
        a10 = FDOT2(v2h{wB0[0],wB0[1]}, p0_, a10); \
        a11 = FDOT2(v2h{wB0[2],wB0[3]}, p1_, a11); \
        a10 = FDOT2(v2h{wB1[0],wB1[1]}, p2_, a10); \
        a11 = FDOT2(v2h{wB1[2],wB1[3]}, p3_, a11); \
        a20 = FDOT2(v2h{wC0[0],wC0[1]}, p0_, a20); \
        a21 = FDOT2(v2h{wC0[2],wC0[3]}, p1_, a21); \
        a20 = FDOT2(v2h{wC1[0],wC1[1]}, p2_, a20); \
        a21 = FDOT2(v2h{wC1[2],wC1[3]}, p3_, a21); \
        a30 = FDOT2(v2h{wD0[0],wD0[1]}, p0_, a30); \
        a31 = FDOT2(v2h{wD0[2],wD0[3]}, p1_, a31); \
        a30 = FDOT2(v2h{wD1[0],wD1[1]}, p2_, a30); \
        a31 = FDOT2(v2h{wD1[2],wD1[3]}, p3_, a31); \
    } } while (0)

// Wave-local recurrence pipeline, one block per batch element, 4 waves
// (= exactly 1 wave per SIMD):
//   w0: layer-0 recurrence (lane = hidden unit, all 4 gates in-lane).
//   w1: layer-1 recurrence, same layout; also stores f32 h for the head.
//   w2: layer-1 input projection, all 4 gate rows, lag 1 phase.
//   w3: output head, lag 3 phases.
// Workgroup barrier once per KP=16 steps; rings double-buffered by phase.
__global__ __launch_bounds__(256)
void lstm2_kernel(const float* __restrict__ x,     // [B,T]
                  const float* __restrict__ h0in,  // [2,B,HD]
                  const float* __restrict__ c0in,  // [2,B,HD]
                  const float* __restrict__ Wih0,  // [4H,1]
                  const float* __restrict__ Whh0,  // [4H,HD]
                  const float* __restrict__ bih0,
                  const float* __restrict__ bhh0,
                  const float* __restrict__ Wih1,  // [4H,HD]
                  const float* __restrict__ Whh1,  // [4H,HD]
                  const float* __restrict__ bih1,
                  const float* __restrict__ bhh1,
                  const float* __restrict__ Wlin,  // [1,HD]
                  const float* __restrict__ blin,  // [1]
                  float* __restrict__ out,         // [B,T]
                  int B, int T)
{
    const int b    = blockIdx.x;
    const int tid  = threadIdx.x;
    const int wave = __builtin_amdgcn_readfirstlane(tid >> 6);  // uniform (SGPR)
    const int lane = tid & 63;

    // Weights (f16, transposed conflict-free layout): 96KB.
    __shared__ __align__(16) v4h wlds[3][4][16][HD];
    __shared__ __align__(16) _Float16 h0ring[NS][HD];        // layer-0 h (f16)
    __shared__ __align__(16) _Float16 h1ring[NS][HD];        // layer-1 h (f16)
    __shared__ __align__(16) float    h1f32[NS][HD + 4];     // layer-1 h (f32, head; +4 pad)
    __shared__ __align__(16) float    xpring[NS][4][HD];     // layer-1 xproj (f32)
    // Total LDS: 98304 + 4096 + 4096 + 8704 + 32768 = 147968 B -> 1 WG/CU.

    // ---- zero-init ring LDS (launch-history independence) ----
    {
        _Float16* z0 = &h0ring[0][0];
        for (int i = tid; i < NS * HD; i += 256) z0[i] = (_Float16)0.f;
        _Float16* z1 = &h1ring[0][0];
        for (int i = tid; i < NS * HD; i += 256) z1[i] = (_Float16)0.f;
        float* z2 = &h1f32[0][0];
        for (int i = tid; i < NS * (HD + 4); i += 256) z2[i] = 0.f;
        float* z3 = &xpring[0][0][0];
        for (int i = tid; i < NS * 4 * HD; i += 256) z3[i] = 0.f;
    }

    // ---- stage all 3 weight matrices into LDS (fully covered: 256 threads
    // x 1 row per matrix; every wlds element written) ----
    {
        const int r = tid;                 // row 0..255
        const int g = r >> 6, j = r & 63;
        const float* srcs[3] = { Whh0, Whh1, Wih1 };
        #pragma unroll
        for (int m = 0; m < 3; ++m) {
            const float4* s4 = (const float4*)(srcs[m] + (size_t)r * HD);
            #pragma unroll
            for (int qq = 0; qq < 16; ++qq) {
                float4 v = s4[qq];
                wlds[m][g][qq][j] =
                    v4h{(_Float16)v.x, (_Float16)v.y, (_Float16)v.z, (_Float16)v.w};
            }
        }
    }
    __syncthreads();

    const int nphase = (T + KP - 1) / KP + 3;

    if (wave == 0) {
        // ================= layer-0 recurrence (weights wlds[0]) =================
        const float b0 = bih0[lane]       + bhh0[lane];
        const float b1 = bih0[64 + lane]  + bhh0[64 + lane];
        const float b2 = bih0[128 + lane] + bhh0[128 + lane];
        const float b3 = bih0[192 + lane] + bhh0[192 + lane];
        const float wx0 = Wih0[lane];       const float wx1 = Wih0[64 + lane];
        const float wx2 = Wih0[128 + lane]; const float wx3 = Wih0[192 + lane];
        float cst = c0in[b * HD + lane];
        h0ring[NS - 1][lane] = (_Float16)h0in[b * HD + lane];
        const float* xrow = x + (size_t)b * T;
        __syncthreads();

        for (int p = 0; p < nphase; ++p) {
            const int t0 = p * KP;
            if (t0 < T) {
                #pragma unroll 1
                for (int k = 0; k < KP; ++k) {
                    const int t = t0 + k;
                    if (t >= T) break;
                    const float xv = xrow[t];                   // uniform scalar load
                    const h8* hp = (const h8*)h0ring[(t + NS - 1) & (NS - 1)];
                    float a00 = b0, a01 = 0.f, a10 = b1, a11 = 0.f;
                    float a20 = b2, a21 = 0.f, a30 = b3, a31 = 0.f;
                    DOTLDS4(0, hp);
                    const float ai = fmaf(wx0, xv, a00 + a01);
                    const float af = fmaf(wx1, xv, a10 + a11);
                    const float ag = fmaf(wx2, xv, a20 + a21);
                    const float ao = fmaf(wx3, xv, a30 + a31);
                    const float iv = fsig(ai), fv = fsig(af);
                    const float gv = ftanh_fast(ag), ov = fsig(ao);
                    cst = fmaf(fv, cst, iv * gv);
                    const float h = ov * ftanh_fast(cst);
                    h0ring[t & (NS - 1)][lane] = (_Float16)h;   // same-wave roundtrip
                }
            }
            __syncthreads();
        }
    } else if (wave == 1) {
        // ============ layer-1 recurrence (weights wlds[1], lag 2 phases) ============
        float cst = c0in[B * HD + b * HD + lane];
        h1ring[NS - 1][lane] = (_Float16)h0in[B * HD + b * HD + lane];
        __syncthreads();

        for (int p = 0; p < nphase; ++p) {
            const int t0 = (p - 2) * KP;
            if (p >= 2 && t0 < T) {
                #pragma unroll 1
                for (int k = 0; k < KP; ++k) {
                    const int t = t0 + k;
                    if (t >= T) break;
                    const int s = t & (NS - 1);
                    const float x0 = xpring[s][0][lane];        // issued early,
                    const float x1 = xpring[s][1][lane];        // consumed after dots
                    const float x2 = xpring[s][2][lane];
                    const float x3 = xpring[s][3][lane];
                    const h8* hp = (const h8*)h1ring[(t + NS - 1) & (NS - 1)];
                    float a00 = 0.f, a01 = 0.f, a10 = 0.f, a11 = 0.f;
                    float a20 = 0.f, a21 = 0.f, a30 = 0.f, a31 = 0.f;
                    DOTLDS4(1, hp);
                    const float ai = x0 + a00 + a01;
                    const float af = x1 + a10 + a11;
                    const float ag = x2 + a20 + a21;
                    const float ao = x3 + a30 + a31;
                    const float iv = fsig(ai), fv = fsig(af);
                    const float gv = ftanh_fast(ag), ov = fsig(ao);
                    cst = fmaf(fv, cst, iv * gv);
                    const float h = ov * ftanh_fast(cst);
                    h1ring[s][lane] = (_Float16)h;
                    h1f32[s][lane]  = h;                        // f32 h for output head
                }
            }
            __syncthreads();
        }
    } else if (wave == 2) {
        // ========= layer-1 input projection (weights wlds[2], lag 1 phase) =========
        const float b0 = bih1[lane]       + bhh1[lane];
        const float b1 = bih1[64 + lane]  + bhh1[64 + lane];
        const float b2 = bih1[128 + lane] + bhh1[128 + lane];
        const float b3 = bih1[192 + lane] + bhh1[192 + lane];
        __syncthreads();

        for (int p = 0; p < nphase; ++p) {
            const int t0 = (p - 1) * KP;
            if (p >= 1 && t0 < T) {
                #pragma unroll 1
                for (int k = 0; k < KP; ++k) {
                    const int t = t0 + k;
                    if (t >= T) break;
                    const int s = t & (NS - 1);
                    const h8* hp = (const h8*)h0ring[s];
                    float a00 = b0, a01 = 0.f, a10 = b1, a11 = 0.f;
                    float a20 = b2, a21 = 0.f, a30 = b3, a31 = 0.f;
                    DOTLDS4(2, hp);
                    xpring[s][0][lane] = a00 + a01;
                    xpring[s][1][lane] = a10 + a11;
                    xpring[s][2][lane] = a20 + a21;
                    xpring[s][3][lane] = a30 + a31;
                }
            }
            __syncthreads();
        }
    } else {
        // ================= output head (lag 3 phases) =================
        const float blin0 = blin[0];
        __syncthreads();

        for (int p = 0; p < nphase; ++p) {
            const int t0 = (p - 3) * KP;
            if (p >= 3 && t0 < T && lane < KP) {
                const int t = t0 + lane;
                if (t < T) {
                    const float4* hv4 = (const float4*)h1f32[t & (NS - 1)];
                    const float4* wp  = (const float4*)Wlin;
                    float acc = blin0;
                    #pragma unroll
                    for (int q = 0; q < 16; ++q) {
                        const float4 hv = hv4[q];
                        const float4 wv = wp[q];
                        acc = fmaf(wv.x, hv.x, acc);
                        acc = fmaf(wv.y, hv.y, acc);
                        acc = fmaf(wv.z, hv.z, acc);
                        acc = fmaf(wv.w, hv.w, acc);
                    }
                    out[(size_t)b * T + t] = acc;
                }
            }
            __syncthreads();
        }
    }
}

extern "C" void kernel_launch(void* const* d_in, const int* in_sizes, int n_in,
                              void* d_out, int out_size, void* d_ws, size_t ws_size,
                              hipStream_t stream)
{
    const float* x    = (const float*)d_in[0];
    const float* h0   = (const float*)d_in[1];
    const float* c0   = (const float*)d_in[2];
    const float* Wih0 = (const float*)d_in[3];
    const float* Whh0 = (const float*)d_in[4];
    const float* bih0 = (const float*)d_in[5];
    const float* bhh0 = (const float*)d_in[6];
    const float* Wih1 = (const float*)d_in[7];
    const float* Whh1 = (const float*)d_in[8];
    const float* bih1 = (const float*)d_in[9];
    const float* bhh1 = (const float*)d_in[10];
    const float* Wlin = (const float*)d_in[11];
    const float* blin = (const float*)d_in[12];
    float* out = (float*)d_out;

    const int B = in_sizes[1] / (2 * HD);   // h0 is [2,B,HD]
    const int T = in_sizes[0] / B;          // input is [B,T]

    lstm2_kernel<<<dim3(B), dim3(256), 0, stream>>>(
        x, h0, c0, Wih0, Whh0, bih0, bhh0,
        Wih1, Whh1, bih1, bhh1, Wlin, blin, out, B, T);
}